// Round 2
// baseline (1286.642 us; speedup 1.0000x reference)
//
#include <hip/hip_runtime.h>
#include <math.h>

#define CCH 64
#define HH 480
#define WW 360
#define KK 32
#define HR 64
#define WR 2048
#define NPIX (HH*WW)            // 172800
#define RFPLANE (HR*WR)         // 131072

// ---------------------------------------------------------------------------
// Weight transpose: [o][ci][kh][kw] -> [ci*9+kh*3+kw][o]  (contiguous in o)
// ---------------------------------------------------------------------------
__global__ __launch_bounds__(256) void k_wt(const float* __restrict__ fw,
                                            const float* __restrict__ aw,
                                            float* __restrict__ wT1,
                                            float* __restrict__ wT2) {
    int t = blockIdx.x * 256 + threadIdx.x;
    if (t < 64 * 1152) {                 // fusion: 64 o x (128ci*9)
        int o = t & 63, r = t >> 6;
        wT1[r * 64 + o] = fw[o * 1152 + r];
    } else {
        int t2 = t - 64 * 1152;
        if (t2 < 64 * 576) {             // attn: 64 o x (64ci*9)
            int o = t2 & 63, r = t2 >> 6;
            wT2[r * 64 + o] = aw[o * 576 + r];
        }
    }
}

// ---------------------------------------------------------------------------
// range_fea [C][Hr][Wr] -> rfT [Hr][Wr][C]   (channel-last for coalesced gather)
// ---------------------------------------------------------------------------
__global__ __launch_bounds__(256) void k_rft(const float* __restrict__ rf,
                                             float* __restrict__ rfT) {
    __shared__ float lds[64][65];
    int y  = blockIdx.y;
    int x0 = blockIdx.x * 64;
    int lx = threadIdx.x & 63;
    int ty = threadIdx.x >> 6;           // 0..3
    #pragma unroll
    for (int cc = 0; cc < 64; cc += 4) {
        int c = cc + ty;
        lds[c][lx] = rf[c * RFPLANE + y * WR + x0 + lx];
    }
    __syncthreads();
    #pragma unroll
    for (int xx = 0; xx < 64; xx += 4) {
        int x = xx + ty;
        rfT[((size_t)(y * WR + x0 + x)) * 64 + lx] = lds[lx][x];
    }
}

// ---------------------------------------------------------------------------
// Flow sampling: one wave per pixel, lane = channel. max over K=32 bilinear taps.
// flow layout per pixel: 64 floats = K*(gy,gx). Writes flow_fea [C][H*W].
// ---------------------------------------------------------------------------
__global__ __launch_bounds__(256) void k_sample(const float* __restrict__ flow,
                                                const float* __restrict__ rfT,
                                                float* __restrict__ ffea) {
    int wid  = threadIdx.x >> 6;
    int lane = threadIdx.x & 63;
    int pid  = blockIdx.x * 4 + wid;
    const float* fp = flow + (size_t)pid * 64;
    float maxv = -3.0e38f;
    #pragma unroll 4
    for (int k = 0; k < KK; k++) {
        float gy = fp[2 * k];
        float gx = fp[2 * k + 1];
        float ix = ((gx + 1.f) * (float)WR - 1.f) * 0.5f;
        float iy = ((gy + 1.f) * (float)HR - 1.f) * 0.5f;
        float x0f = floorf(ix), y0f = floorf(iy);
        float wx = ix - x0f, wy = iy - y0f;
        int x0 = (int)x0f, y0 = (int)y0f;
        bool xv0 = ((unsigned)x0 < WR);
        bool xv1 = ((unsigned)(x0 + 1) < WR);
        bool yv0 = ((unsigned)y0 < HR);
        bool yv1 = ((unsigned)(y0 + 1) < HR);
        int xc0 = x0 < 0 ? 0 : x0;
        int xc1 = (x0 + 1 > WR - 1) ? WR - 1 : x0 + 1;
        int yc0 = y0 < 0 ? 0 : y0;
        int yc1 = (y0 + 1 > HR - 1) ? HR - 1 : y0 + 1;
        float w00 = (xv0 && yv0) ? (1.f - wy) * (1.f - wx) : 0.f;
        float w01 = (xv1 && yv0) ? (1.f - wy) * wx         : 0.f;
        float w10 = (xv0 && yv1) ? wy * (1.f - wx)         : 0.f;
        float w11 = (xv1 && yv1) ? wy * wx                 : 0.f;
        const float* r0 = rfT + ((size_t)(yc0 * WR)) * 64;
        const float* r1 = rfT + ((size_t)(yc1 * WR)) * 64;
        float v =      w00 * r0[(size_t)xc0 * 64 + lane];
        v = fmaf(w01,  r0[(size_t)xc1 * 64 + lane], v);
        v = fmaf(w10,  r1[(size_t)xc0 * 64 + lane], v);
        v = fmaf(w11,  r1[(size_t)xc1 * 64 + lane], v);
        maxv = fmaxf(maxv, v);
    }
    ffea[(size_t)lane * NPIX + pid] = maxv;
}

// ---------------------------------------------------------------------------
// Conv1 (fusion): 3x3, in=concat(polar,flow_fea) 128ch, out 64ch, BN+ReLU.
// Thread per pixel; acc[64]; weights via wave-uniform scalar loads from wT1.
// ---------------------------------------------------------------------------
__global__ __launch_bounds__(256) void k_conv1(const float* __restrict__ polar,
                                               const float* __restrict__ ffea,
                                               const float* __restrict__ wT1,
                                               const float* __restrict__ g,
                                               const float* __restrict__ b,
                                               const float* __restrict__ mn,
                                               const float* __restrict__ vr,
                                               float* __restrict__ res) {
    int p = blockIdx.x * 256 + threadIdx.x;      // 675 blocks exactly
    int h = p / WW, w = p - h * WW;
    int xm = (w == 0) ? WW - 1 : w - 1;
    int xp = (w == WW - 1) ? 0 : w + 1;
    float acc[64];
    #pragma unroll
    for (int o = 0; o < 64; o++) acc[o] = 0.f;
    for (int ci = 0; ci < 128; ci++) {
        const float* plane = (ci < 64) ? (polar + (size_t)ci * NPIX)
                                       : (ffea + (size_t)(ci - 64) * NPIX);
        #pragma unroll
        for (int kh = 0; kh < 3; kh++) {
            int y = h + kh - 1;
            if ((unsigned)y >= HH) continue;
            const float* row = plane + (size_t)y * WW;
            float v0 = row[xm], v1 = row[w], v2 = row[xp];
            const float* wt = wT1 + (size_t)(ci * 9 + kh * 3) * 64;
            #pragma unroll
            for (int o = 0; o < 64; o++) acc[o] = fmaf(v0, wt[o],       acc[o]);
            #pragma unroll
            for (int o = 0; o < 64; o++) acc[o] = fmaf(v1, wt[64 + o],  acc[o]);
            #pragma unroll
            for (int o = 0; o < 64; o++) acc[o] = fmaf(v2, wt[128 + o], acc[o]);
        }
    }
    #pragma unroll
    for (int o = 0; o < 64; o++) {
        float inv = g[o] * rsqrtf(vr[o] + 1e-5f);
        float bb  = b[o] - mn[o] * inv;
        float r   = fmaf(acc[o], inv, bb);
        res[(size_t)o * NPIX + p] = fmaxf(r, 0.f);
    }
}

// ---------------------------------------------------------------------------
// Conv2 (attn) + BN + channel softmax + final output = polar + res*att
// ---------------------------------------------------------------------------
__global__ __launch_bounds__(256) void k_conv2(const float* __restrict__ resv,
                                               const float* __restrict__ polar,
                                               const float* __restrict__ wT2,
                                               const float* __restrict__ g,
                                               const float* __restrict__ b,
                                               const float* __restrict__ mn,
                                               const float* __restrict__ vr,
                                               float* __restrict__ out) {
    int p = blockIdx.x * 256 + threadIdx.x;
    int h = p / WW, w = p - h * WW;
    int xm = (w == 0) ? WW - 1 : w - 1;
    int xp = (w == WW - 1) ? 0 : w + 1;
    float acc[64];
    #pragma unroll
    for (int o = 0; o < 64; o++) acc[o] = 0.f;
    for (int ci = 0; ci < 64; ci++) {
        const float* plane = resv + (size_t)ci * NPIX;
        #pragma unroll
        for (int kh = 0; kh < 3; kh++) {
            int y = h + kh - 1;
            if ((unsigned)y >= HH) continue;
            const float* row = plane + (size_t)y * WW;
            float v0 = row[xm], v1 = row[w], v2 = row[xp];
            const float* wt = wT2 + (size_t)(ci * 9 + kh * 3) * 64;
            #pragma unroll
            for (int o = 0; o < 64; o++) acc[o] = fmaf(v0, wt[o],       acc[o]);
            #pragma unroll
            for (int o = 0; o < 64; o++) acc[o] = fmaf(v1, wt[64 + o],  acc[o]);
            #pragma unroll
            for (int o = 0; o < 64; o++) acc[o] = fmaf(v2, wt[128 + o], acc[o]);
        }
    }
    // BN -> softmax over the 64 channels this thread owns
    float m = -3.0e38f;
    #pragma unroll
    for (int o = 0; o < 64; o++) {
        float inv = g[o] * rsqrtf(vr[o] + 1e-5f);
        float bb  = b[o] - mn[o] * inv;
        acc[o] = fmaf(acc[o], inv, bb);
        m = fmaxf(m, acc[o]);
    }
    float s = 0.f;
    #pragma unroll
    for (int o = 0; o < 64; o++) {
        acc[o] = __expf(acc[o] - m);
        s += acc[o];
    }
    float rinv = 1.f / s;
    #pragma unroll
    for (int o = 0; o < 64; o++) {
        float att = acc[o] * rinv;
        size_t idx = (size_t)o * NPIX + p;
        out[idx] = fmaf(resv[idx], att, polar[idx]);
    }
}

// ---------------------------------------------------------------------------
extern "C" void kernel_launch(void* const* d_in, const int* in_sizes, int n_in,
                              void* d_out, int out_size, void* d_ws, size_t ws_size,
                              hipStream_t stream) {
    const float* flow  = (const float*)d_in[0];
    const float* polar = (const float*)d_in[1];
    const float* rf    = (const float*)d_in[2];
    const float* fw    = (const float*)d_in[3];
    const float* fg    = (const float*)d_in[4];
    const float* fb    = (const float*)d_in[5];
    const float* fm    = (const float*)d_in[6];
    const float* fv    = (const float*)d_in[7];
    const float* aw    = (const float*)d_in[8];
    const float* ag    = (const float*)d_in[9];
    const float* ab    = (const float*)d_in[10];
    const float* am    = (const float*)d_in[11];
    const float* av    = (const float*)d_in[12];
    float* out = (float*)d_out;

    float* ws   = (float*)d_ws;
    float* rfT  = ws;                        // 8,388,608 f32 (33.5 MB)
    float* ffea = rfT + (size_t)8388608;     // 11,059,200 f32 (44.2 MB)
    float* res  = ffea + (size_t)11059200;   // 11,059,200 f32 (44.2 MB)
    float* wT1  = res + (size_t)11059200;    // 73,728 f32
    float* wT2  = wT1 + (size_t)73728;       // 36,864 f32

    k_wt<<<432, 256, 0, stream>>>(fw, aw, wT1, wT2);
    k_rft<<<dim3(32, 64), 256, 0, stream>>>(rf, rfT);
    k_sample<<<NPIX / 4, 256, 0, stream>>>(flow, rfT, ffea);
    k_conv1<<<NPIX / 256, 256, 0, stream>>>(polar, ffea, wT1, fg, fb, fm, fv, res);
    k_conv2<<<NPIX / 256, 256, 0, stream>>>(res, polar, wT2, ag, ab, am, av, out);
}

// Round 3
// 462.998 us; speedup vs baseline: 2.7789x; 2.7789x over previous
//
#include <hip/hip_runtime.h>
#include <math.h>

#define CCH 64
#define HH 480
#define WW 360
#define KK 32
#define HR 64
#define WR 2048
#define NPIX (HH*WW)            // 172800
#define RFNPIX (HR*WR)          // 131072
#define ZOFF 16777216u          // byte offset of zero-land line in rfT16

typedef __attribute__((ext_vector_type(8))) short short8;
typedef __attribute__((ext_vector_type(4))) float f32x4;
typedef __attribute__((ext_vector_type(4))) int  int4_;

__device__ __forceinline__ ushort f2bf(float f) {        // RTN f32->bf16
    uint u = __float_as_uint(f);
    return (ushort)((u + 0x7fffu + ((u >> 16) & 1u)) >> 16);
}

// ---------------------------------------------------------------------------
// Weight prep: pack conv weights into MFMA A-fragment order, bf16.
// wA1 layout: [chunk(4)][tap(9)][Mf(4)][lane(64)][j(8)]
//   o = Mf*16 + (lane&15), ci = chunk*32 + (lane>>4)*8 + j, tap = kh*3+kw
// ---------------------------------------------------------------------------
__global__ __launch_bounds__(256) void k_wprep(const float* __restrict__ fw,
                                               const float* __restrict__ aw,
                                               ushort* __restrict__ wA1,
                                               ushort* __restrict__ wA2) {
    int t = blockIdx.x * 256 + threadIdx.x;
    if (t < 73728) {                                   // conv1: 4 chunks (128 ci)
        int j = t & 7, ln = (t >> 3) & 63, Mf = (t >> 9) & 3, rem = t >> 11;
        int tap = rem % 9, c = rem / 9;
        int o = Mf * 16 + (ln & 15);
        int ci = c * 32 + ((ln >> 4) & 3) * 8 + j;
        wA1[t] = f2bf(fw[(o * 128 + ci) * 9 + tap]);
    } else if (t < 73728 + 36864) {                    // conv2: 2 chunks (64 ci)
        int i = t - 73728;
        int j = i & 7, ln = (i >> 3) & 63, Mf = (i >> 9) & 3, rem = i >> 11;
        int tap = rem % 9, c = rem / 9;
        int o = Mf * 16 + (ln & 15);
        int ci = c * 32 + ((ln >> 4) & 3) * 8 + j;
        wA2[i] = f2bf(aw[(o * 64 + ci) * 9 + tap]);
    }
}

// ---------------------------------------------------------------------------
// Transpose f32 [64][npix] -> bf16 channel-last [npix][rowShorts] (cols 0..63)
// ---------------------------------------------------------------------------
__global__ __launch_bounds__(256) void k_tr(const float* __restrict__ src,
                                            ushort* __restrict__ dst,
                                            int npix, int rowShorts) {
    __shared__ float lds[64][65];
    int t = threadIdx.x;
    int pix0 = blockIdx.x * 64;
    int lx = t & 63, ty = t >> 6;
    #pragma unroll
    for (int cc = 0; cc < 64; cc += 4) {
        int c = cc + ty;
        lds[c][lx] = src[(size_t)c * npix + pix0 + lx];
    }
    __syncthreads();
    int cp = t & 31, po = t >> 5;        // cp = channel pair, po = pixel offset
    #pragma unroll
    for (int pl = po; pl < 64; pl += 8) {
        uint u = (uint)f2bf(lds[2 * cp][pl]) | ((uint)f2bf(lds[2 * cp + 1][pl]) << 16);
        *(uint*)(dst + (size_t)(pix0 + pl) * rowShorts + cp * 2) = u;
    }
}

__global__ void k_zero(uint* __restrict__ rft32) {
    if (threadIdx.x < 32) rft32[(ZOFF >> 2) + threadIdx.x] = 0;
}

// ---------------------------------------------------------------------------
// Flow sampling v2: 2 pixels per wave. Lane L<32 preps (pixelA, k=L); lane>=32
// preps (pixelB, k=L-32): 4 corner byte-offsets (zero-land if invalid) + 4
// weights. Gather loop broadcasts via readlane; each lane gathers a bf16x2
// channel pair (lane&31 -> channels 2c,2c+1) for its half's pixel.
// Writes xin[p][64+c] bf16.
// ---------------------------------------------------------------------------
__global__ __launch_bounds__(256) void k_sample(const float* __restrict__ flow,
                                                const char* __restrict__ rftb,
                                                ushort* __restrict__ xin) {
    int tid = threadIdx.x;
    int ln = tid & 63;
    bool loHalf = ln < 32;
    int gwave = blockIdx.x * 4 + (tid >> 6);
    int pA = gwave * 2, pB = pA + 1;

    // ---- prep (per-lane: one (pixel,k)) ----
    int k = ln & 31;
    int pix = loHalf ? pA : pB;
    const float* fp = flow + (size_t)pix * 64 + 2 * k;
    float gy = fp[0], gx = fp[1];
    float ix = fmaf(gx, 1024.f, 1023.5f);
    float iy = fmaf(gy, 32.f, 31.5f);
    float xf = floorf(ix), yf = floorf(iy);
    float wx = ix - xf, wy = iy - yf;
    int x0 = (int)xf, y0 = (int)yf;
    bool xv0 = (unsigned)x0 < (unsigned)WR;
    bool xv1 = (unsigned)(x0 + 1) < (unsigned)WR;
    bool yv0 = (unsigned)y0 < (unsigned)HR;
    bool yv1 = (unsigned)(y0 + 1) < (unsigned)HR;
    int xc0 = x0 < 0 ? 0 : x0;
    int xc1 = x0 + 1 > WR - 1 ? WR - 1 : x0 + 1;
    int yc0 = y0 < 0 ? 0 : y0;
    int yc1 = y0 + 1 > HR - 1 ? HR - 1 : y0 + 1;
    uint o00 = (xv0 && yv0) ? (uint)(((yc0 << 11) + xc0) << 7) : ZOFF;
    uint o01 = (xv1 && yv0) ? (uint)(((yc0 << 11) + xc1) << 7) : ZOFF;
    uint o10 = (xv0 && yv1) ? (uint)(((yc1 << 11) + xc0) << 7) : ZOFF;
    uint o11 = (xv1 && yv1) ? (uint)(((yc1 << 11) + xc1) << 7) : ZOFF;
    float w00 = (1.f - wy) * (1.f - wx);
    float w01 = (1.f - wy) * wx;
    float w10 = wy * (1.f - wx);
    float w11 = wy * wx;
    int iw00 = __float_as_int(w00), iw01 = __float_as_int(w01);
    int iw10 = __float_as_int(w10), iw11 = __float_as_int(w11);

    uint laneByte = (uint)((ln & 31) * 4);
    float mLo = -3.0e38f, mHi = -3.0e38f;

    // ---- gather loop ----
    #pragma unroll
    for (int kk = 0; kk < 32; kk++) {
        uint a0 = (uint)__builtin_amdgcn_readlane((int)o00, kk);
        uint a1 = (uint)__builtin_amdgcn_readlane((int)o01, kk);
        uint a2 = (uint)__builtin_amdgcn_readlane((int)o10, kk);
        uint a3 = (uint)__builtin_amdgcn_readlane((int)o11, kk);
        uint b0 = (uint)__builtin_amdgcn_readlane((int)o00, kk + 32);
        uint b1 = (uint)__builtin_amdgcn_readlane((int)o01, kk + 32);
        uint b2 = (uint)__builtin_amdgcn_readlane((int)o10, kk + 32);
        uint b3 = (uint)__builtin_amdgcn_readlane((int)o11, kk + 32);
        float wa0 = __int_as_float(__builtin_amdgcn_readlane(iw00, kk));
        float wa1 = __int_as_float(__builtin_amdgcn_readlane(iw01, kk));
        float wa2 = __int_as_float(__builtin_amdgcn_readlane(iw10, kk));
        float wa3 = __int_as_float(__builtin_amdgcn_readlane(iw11, kk));
        float wb0 = __int_as_float(__builtin_amdgcn_readlane(iw00, kk + 32));
        float wb1 = __int_as_float(__builtin_amdgcn_readlane(iw01, kk + 32));
        float wb2 = __int_as_float(__builtin_amdgcn_readlane(iw10, kk + 32));
        float wb3 = __int_as_float(__builtin_amdgcn_readlane(iw11, kk + 32));

        uint f0 = (loHalf ? a0 : b0) + laneByte;
        uint f1 = (loHalf ? a1 : b1) + laneByte;
        uint f2 = (loHalf ? a2 : b2) + laneByte;
        uint f3 = (loHalf ? a3 : b3) + laneByte;
        uint d0 = *(const uint*)(rftb + f0);
        uint d1 = *(const uint*)(rftb + f1);
        uint d2 = *(const uint*)(rftb + f2);
        uint d3 = *(const uint*)(rftb + f3);
        float W0 = loHalf ? wa0 : wb0;
        float W1 = loHalf ? wa1 : wb1;
        float W2 = loHalf ? wa2 : wb2;
        float W3 = loHalf ? wa3 : wb3;

        float vlo = W0 * __uint_as_float(d0 << 16);
        vlo = fmaf(W1, __uint_as_float(d1 << 16), vlo);
        vlo = fmaf(W2, __uint_as_float(d2 << 16), vlo);
        vlo = fmaf(W3, __uint_as_float(d3 << 16), vlo);
        float vhi = W0 * __uint_as_float(d0 & 0xffff0000u);
        vhi = fmaf(W1, __uint_as_float(d1 & 0xffff0000u), vhi);
        vhi = fmaf(W2, __uint_as_float(d2 & 0xffff0000u), vhi);
        vhi = fmaf(W3, __uint_as_float(d3 & 0xffff0000u), vhi);
        mLo = fmaxf(mLo, vlo);
        mHi = fmaxf(mHi, vhi);
    }

    uint outw;
    asm("v_cvt_pk_bf16_f32 %0, %1, %2" : "=v"(outw) : "v"(mLo), "v"(mHi));
    // channels 2c (low), 2c+1 (high) of pixel; flow half at cols 64..127
    *(uint*)((char*)xin + (size_t)pix * 256 + 128 + (ln & 31) * 4) = outw;
}

// ---------------------------------------------------------------------------
// conv1: implicit-GEMM MFMA, M=64(o), N=192 (180-px half-row + pad), K=1152.
// Input xin bf16 [p][128]. Output res_t f32 [p][64] (BN+ReLU applied).
// ---------------------------------------------------------------------------
__global__ __launch_bounds__(256) void k_mconv1(const ushort* __restrict__ xin,
                                                const ushort* __restrict__ wA,
                                                const float* __restrict__ g,
                                                const float* __restrict__ b,
                                                const float* __restrict__ mn,
                                                const float* __restrict__ vr,
                                                float* __restrict__ res_t) {
    __shared__ __align__(16) ushort xt[3][194][32];
    int tid = threadIdx.x;
    int h = blockIdx.x >> 1, w0 = (blockIdx.x & 1) * 180;
    int wid = tid >> 6, ln = tid & 63;
    f32x4 acc[4][3];
    #pragma unroll
    for (int m = 0; m < 4; m++)
        #pragma unroll
        for (int nf = 0; nf < 3; nf++) acc[m][nf] = (f32x4){0.f, 0.f, 0.f, 0.f};

    for (int c = 0; c < 4; c++) {
        __syncthreads();
        for (int i = tid; i < 2184; i += 256) {          // 546 slots x 4 quads
            int q = i & 3, s = i >> 2;
            int r = s / 182, pw = s - r * 182;
            int gh = h + r - 1;
            int gw = w0 + pw - 1;
            if (gw < 0) gw += WW;
            if (gw >= WW) gw -= WW;
            int4_ val = {0, 0, 0, 0};
            if ((unsigned)gh < (unsigned)HH)
                val = *(const int4_*)(xin + ((size_t)(gh * WW + gw) * 128 + c * 32 + q * 8));
            *(int4_*)&xt[r][pw][(q ^ (pw & 3)) * 8] = val;
        }
        __syncthreads();
        #pragma unroll
        for (int tap = 0; tap < 9; tap++) {
            int dh = tap / 3, dw = tap % 3;
            short8 aF[4];
            #pragma unroll
            for (int m = 0; m < 4; m++)
                aF[m] = *(const short8*)(wA + (size_t)(((c * 9 + tap) * 4 + m) * 64 + ln) * 8);
            short8 bF[3];
            #pragma unroll
            for (int nf = 0; nf < 3; nf++) {
                int pw = wid * 48 + nf * 16 + (ln & 15) + dw;
                bF[nf] = *(const short8*)&xt[dh][pw][((((ln >> 4) & 3)) ^ (pw & 3)) * 8];
            }
            #pragma unroll
            for (int m = 0; m < 4; m++)
                #pragma unroll
                for (int nf = 0; nf < 3; nf++)
                    acc[m][nf] = __builtin_amdgcn_mfma_f32_16x16x32_bf16(aF[m], bF[nf], acc[m][nf], 0, 0, 0);
        }
    }
    // epilogue: BN + ReLU -> res_t[p][o]
    #pragma unroll
    for (int m = 0; m < 4; m++) {
        #pragma unroll
        for (int reg = 0; reg < 4; reg++) {
            int o = m * 16 + ((ln >> 4) & 3) * 4 + reg;
            float sc = g[o] * rsqrtf(vr[o] + 1e-5f);
            float bi = b[o] - mn[o] * sc;
            #pragma unroll
            for (int nf = 0; nf < 3; nf++) {
                int n = wid * 48 + nf * 16 + (ln & 15);
                if (n < 180) {
                    int P = h * WW + w0 + n;
                    float v = fmaf(acc[m][nf][reg], sc, bi);
                    res_t[(size_t)P * 64 + o] = fmaxf(v, 0.f);
                }
            }
        }
    }
}

// ---------------------------------------------------------------------------
// conv2: same GEMM (K=576) on res_t (f32 -> bf16 staged), BN + channel
// softmax + final out = polar + res*att.
// ---------------------------------------------------------------------------
__global__ __launch_bounds__(256) void k_mconv2(const float* __restrict__ res_t,
                                                const float* __restrict__ polar,
                                                const ushort* __restrict__ wA,
                                                const float* __restrict__ g,
                                                const float* __restrict__ b,
                                                const float* __restrict__ mn,
                                                const float* __restrict__ vr,
                                                float* __restrict__ out) {
    __shared__ __align__(16) ushort xt[3][194][32];
    int tid = threadIdx.x;
    int h = blockIdx.x >> 1, w0 = (blockIdx.x & 1) * 180;
    int wid = tid >> 6, ln = tid & 63;
    f32x4 acc[4][3];
    #pragma unroll
    for (int m = 0; m < 4; m++)
        #pragma unroll
        for (int nf = 0; nf < 3; nf++) acc[m][nf] = (f32x4){0.f, 0.f, 0.f, 0.f};

    for (int c = 0; c < 2; c++) {
        __syncthreads();
        for (int i = tid; i < 2184; i += 256) {
            int q = i & 3, s = i >> 2;
            int r = s / 182, pw = s - r * 182;
            int gh = h + r - 1;
            int gw = w0 + pw - 1;
            if (gw < 0) gw += WW;
            if (gw >= WW) gw -= WW;
            int4_ val = {0, 0, 0, 0};
            if ((unsigned)gh < (unsigned)HH) {
                const float* src = res_t + ((size_t)(gh * WW + gw) * 64 + c * 32 + q * 8);
                f32x4 va = *(const f32x4*)src;
                f32x4 vb = *(const f32x4*)(src + 4);
                uint u0, u1, u2, u3;
                asm("v_cvt_pk_bf16_f32 %0, %1, %2" : "=v"(u0) : "v"(va[0]), "v"(va[1]));
                asm("v_cvt_pk_bf16_f32 %0, %1, %2" : "=v"(u1) : "v"(va[2]), "v"(va[3]));
                asm("v_cvt_pk_bf16_f32 %0, %1, %2" : "=v"(u2) : "v"(vb[0]), "v"(vb[1]));
                asm("v_cvt_pk_bf16_f32 %0, %1, %2" : "=v"(u3) : "v"(vb[2]), "v"(vb[3]));
                val = (int4_){(int)u0, (int)u1, (int)u2, (int)u3};
            }
            *(int4_*)&xt[r][pw][(q ^ (pw & 3)) * 8] = val;
        }
        __syncthreads();
        #pragma unroll
        for (int tap = 0; tap < 9; tap++) {
            int dh = tap / 3, dw = tap % 3;
            short8 aF[4];
            #pragma unroll
            for (int m = 0; m < 4; m++)
                aF[m] = *(const short8*)(wA + (size_t)(((c * 9 + tap) * 4 + m) * 64 + ln) * 8);
            short8 bF[3];
            #pragma unroll
            for (int nf = 0; nf < 3; nf++) {
                int pw = wid * 48 + nf * 16 + (ln & 15) + dw;
                bF[nf] = *(const short8*)&xt[dh][pw][((((ln >> 4) & 3)) ^ (pw & 3)) * 8];
            }
            #pragma unroll
            for (int m = 0; m < 4; m++)
                #pragma unroll
                for (int nf = 0; nf < 3; nf++)
                    acc[m][nf] = __builtin_amdgcn_mfma_f32_16x16x32_bf16(aF[m], bF[nf], acc[m][nf], 0, 0, 0);
        }
    }
    // epilogue: BN -> softmax over 64 channels -> out = polar + res*att
    #pragma unroll
    for (int m = 0; m < 4; m++) {
        #pragma unroll
        for (int reg = 0; reg < 4; reg++) {
            int o = m * 16 + ((ln >> 4) & 3) * 4 + reg;
            float sc = g[o] * rsqrtf(vr[o] + 1e-5f);
            float bi = b[o] - mn[o] * sc;
            #pragma unroll
            for (int nf = 0; nf < 3; nf++)
                acc[m][nf][reg] = fmaf(acc[m][nf][reg], sc, bi);
        }
    }
    #pragma unroll
    for (int nf = 0; nf < 3; nf++) {
        float mx = -3.0e38f;
        #pragma unroll
        for (int m = 0; m < 4; m++)
            #pragma unroll
            for (int reg = 0; reg < 4; reg++) mx = fmaxf(mx, acc[m][nf][reg]);
        mx = fmaxf(mx, __shfl_xor(mx, 16));
        mx = fmaxf(mx, __shfl_xor(mx, 32));
        float s = 0.f;
        #pragma unroll
        for (int m = 0; m < 4; m++)
            #pragma unroll
            for (int reg = 0; reg < 4; reg++) {
                float e = __expf(acc[m][nf][reg] - mx);
                acc[m][nf][reg] = e;
                s += e;
            }
        s += __shfl_xor(s, 16);
        s += __shfl_xor(s, 32);
        float rinv = 1.f / s;
        int n = wid * 48 + nf * 16 + (ln & 15);
        if (n < 180) {
            int P = h * WW + w0 + n;
            #pragma unroll
            for (int m = 0; m < 4; m++)
                #pragma unroll
                for (int reg = 0; reg < 4; reg++) {
                    int o = m * 16 + ((ln >> 4) & 3) * 4 + reg;
                    float att = acc[m][nf][reg] * rinv;
                    out[(size_t)o * NPIX + P] =
                        fmaf(res_t[(size_t)P * 64 + o], att, polar[(size_t)o * NPIX + P]);
                }
        }
    }
}

// ---------------------------------------------------------------------------
extern "C" void kernel_launch(void* const* d_in, const int* in_sizes, int n_in,
                              void* d_out, int out_size, void* d_ws, size_t ws_size,
                              hipStream_t stream) {
    const float* flow  = (const float*)d_in[0];
    const float* polar = (const float*)d_in[1];
    const float* rf    = (const float*)d_in[2];
    const float* fw    = (const float*)d_in[3];
    const float* fg    = (const float*)d_in[4];
    const float* fb    = (const float*)d_in[5];
    const float* fm    = (const float*)d_in[6];
    const float* fv    = (const float*)d_in[7];
    const float* aw    = (const float*)d_in[8];
    const float* ag    = (const float*)d_in[9];
    const float* ab    = (const float*)d_in[10];
    const float* am    = (const float*)d_in[11];
    const float* av    = (const float*)d_in[12];
    float* out = (float*)d_out;

    char* wsb = (char*)d_ws;
    ushort* xin   = (ushort*)wsb;                         // [NPIX][128] bf16 = 44,236,800 B
    ushort* rft   = (ushort*)(wsb + 44236800);            // [RFNPIX][64] bf16 + 128B zero-land
    float*  res_t = (float*)(wsb + 61014272);             // [NPIX][64] f32 = 44,236,800 B
    ushort* wA1   = (ushort*)(wsb + 105251072);           // 147,456 B
    ushort* wA2   = wA1 + 73728;                          // 73,728 B

    k_wprep<<<432, 256, 0, stream>>>(fw, aw, wA1, wA2);
    k_tr<<<NPIX / 64, 256, 0, stream>>>(polar, xin, NPIX, 128);
    k_tr<<<RFNPIX / 64, 256, 0, stream>>>(rf, rft, RFNPIX, 64);
    k_zero<<<1, 64, 0, stream>>>((uint*)rft);
    k_sample<<<NPIX / 8, 256, 0, stream>>>(flow, (const char*)rft, xin);
    k_mconv1<<<960, 256, 0, stream>>>(xin, wA1, fg, fb, fm, fv, res_t);
    k_mconv2<<<960, 256, 0, stream>>>(res_t, polar, wA2, ag, ab, am, av, out);
}

// Round 4
// 456.349 us; speedup vs baseline: 2.8194x; 1.0146x over previous
//
#include <hip/hip_runtime.h>
#include <math.h>

#define CCH 64
#define HH 480
#define WW 360
#define KK 32
#define HR 64
#define WR 2048
#define NPIX (HH*WW)            // 172800
#define RFNPIX (HR*WR)          // 131072
#define ZOFF 16777216u          // byte offset of zero-land line in rfT16

typedef __attribute__((ext_vector_type(8))) short short8;
typedef __attribute__((ext_vector_type(4))) float f32x4;
typedef __attribute__((ext_vector_type(4))) int  int4_;

__device__ __forceinline__ ushort f2bf(float f) {        // RTN f32->bf16
    uint u = __float_as_uint(f);
    return (ushort)((u + 0x7fffu + ((u >> 16) & 1u)) >> 16);
}

// ---------------------------------------------------------------------------
// Weight prep: pack conv weights into MFMA A-fragment order, bf16.
// wA1 layout: [chunk(4)][tap(9)][Mf(4)][lane(64)][j(8)]
//   o = Mf*16 + (lane&15), ci = chunk*32 + (lane>>4)*8 + j, tap = kh*3+kw
// ---------------------------------------------------------------------------
__global__ __launch_bounds__(256) void k_wprep(const float* __restrict__ fw,
                                               const float* __restrict__ aw,
                                               ushort* __restrict__ wA1,
                                               ushort* __restrict__ wA2) {
    int t = blockIdx.x * 256 + threadIdx.x;
    if (t < 73728) {                                   // conv1: 4 chunks (128 ci)
        int j = t & 7, ln = (t >> 3) & 63, Mf = (t >> 9) & 3, rem = t >> 11;
        int tap = rem % 9, c = rem / 9;
        int o = Mf * 16 + (ln & 15);
        int ci = c * 32 + ((ln >> 4) & 3) * 8 + j;
        wA1[t] = f2bf(fw[(o * 128 + ci) * 9 + tap]);
    } else if (t < 73728 + 36864) {                    // conv2: 2 chunks (64 ci)
        int i = t - 73728;
        int j = i & 7, ln = (i >> 3) & 63, Mf = (i >> 9) & 3, rem = i >> 11;
        int tap = rem % 9, c = rem / 9;
        int o = Mf * 16 + (ln & 15);
        int ci = c * 32 + ((ln >> 4) & 3) * 8 + j;
        wA2[i] = f2bf(aw[(o * 64 + ci) * 9 + tap]);
    }
}

// ---------------------------------------------------------------------------
// Transpose f32 [64][npix] -> bf16 channel-last [npix][rowShorts] (cols 0..63)
// ---------------------------------------------------------------------------
__global__ __launch_bounds__(256) void k_tr(const float* __restrict__ src,
                                            ushort* __restrict__ dst,
                                            int npix, int rowShorts) {
    __shared__ float lds[64][65];
    int t = threadIdx.x;
    int pix0 = blockIdx.x * 64;
    int lx = t & 63, ty = t >> 6;
    #pragma unroll
    for (int cc = 0; cc < 64; cc += 4) {
        int c = cc + ty;
        lds[c][lx] = src[(size_t)c * npix + pix0 + lx];
    }
    __syncthreads();
    int cp = t & 31, po = t >> 5;        // cp = channel pair, po = pixel offset
    #pragma unroll
    for (int pl = po; pl < 64; pl += 8) {
        uint u = (uint)f2bf(lds[2 * cp][pl]) | ((uint)f2bf(lds[2 * cp + 1][pl]) << 16);
        *(uint*)(dst + (size_t)(pix0 + pl) * rowShorts + cp * 2) = u;
    }
}

__global__ void k_zero(uint* __restrict__ rft32) {
    if (threadIdx.x < 32) rft32[(ZOFF >> 2) + threadIdx.x] = 0;
}

// ---------------------------------------------------------------------------
// Flow sampling v3: 2 pixels per wave. Prep (one (pixel,k) per lane) computes
// 4 corner byte-offsets (zero-land if invalid) + 4 weights, stores them in
// LDS. The gather loop re-reads them with wave-uniform ds_read_b64 (lo half
// broadcasts pixel A's entry, hi half pixel B's) -- replaces 16 readlane +
// 8 cndmask per k with 4 DS ops on the LDS pipe. Each lane gathers a bf16x2
// channel pair (lane&31 -> channels 2c,2c+1). Writes xin[p][64..127] bf16.
// ---------------------------------------------------------------------------
__global__ __launch_bounds__(256) void k_sample(const float* __restrict__ flow,
                                                const char* __restrict__ rftb,
                                                ushort* __restrict__ xin) {
    __shared__ __align__(16) uint pbuf[4][2][32][8];   // [wave][half][k][(off,w)x4]
    int tid = threadIdx.x;
    int ln = tid & 63;
    int wid = tid >> 6;
    int half = ln >> 5;
    int gwave = blockIdx.x * 4 + wid;

    // ---- prep (per-lane: one (pixel,k)) ----
    int k = ln & 31;
    int pix = gwave * 2 + half;
    const float* fp = flow + (size_t)pix * 64 + 2 * k;
    float gy = fp[0], gx = fp[1];
    float ix = fmaf(gx, 1024.f, 1023.5f);
    float iy = fmaf(gy, 32.f, 31.5f);
    float xf = floorf(ix), yf = floorf(iy);
    float wx = ix - xf, wy = iy - yf;
    int x0 = (int)xf, y0 = (int)yf;
    bool xv0 = (unsigned)x0 < (unsigned)WR;
    bool xv1 = (unsigned)(x0 + 1) < (unsigned)WR;
    bool yv0 = (unsigned)y0 < (unsigned)HR;
    bool yv1 = (unsigned)(y0 + 1) < (unsigned)HR;
    int xc0 = x0 < 0 ? 0 : x0;
    int xc1 = x0 + 1 > WR - 1 ? WR - 1 : x0 + 1;
    int yc0 = y0 < 0 ? 0 : y0;
    int yc1 = y0 + 1 > HR - 1 ? HR - 1 : y0 + 1;
    uint o00 = (xv0 && yv0) ? (uint)(((yc0 << 11) + xc0) << 7) : ZOFF;
    uint o01 = (xv1 && yv0) ? (uint)(((yc0 << 11) + xc1) << 7) : ZOFF;
    uint o10 = (xv0 && yv1) ? (uint)(((yc1 << 11) + xc0) << 7) : ZOFF;
    uint o11 = (xv1 && yv1) ? (uint)(((yc1 << 11) + xc1) << 7) : ZOFF;
    float w00 = (1.f - wy) * (1.f - wx);
    float w01 = (1.f - wy) * wx;
    float w10 = wy * (1.f - wx);
    float w11 = wy * wx;
    *(int4_*)&pbuf[wid][half][k][0] =
        (int4_){(int)o00, __float_as_int(w00), (int)o01, __float_as_int(w01)};
    *(int4_*)&pbuf[wid][half][k][4] =
        (int4_){(int)o10, __float_as_int(w10), (int)o11, __float_as_int(w11)};
    __syncthreads();

    uint laneByte = (uint)((ln & 31) * 4);
    const uint* pb = &pbuf[wid][half][0][0];
    float mLo = -3.0e38f, mHi = -3.0e38f;

    // ---- gather loop ----
    #pragma unroll
    for (int kk = 0; kk < 32; kk++) {
        uint2 e0 = *(const uint2*)(pb + kk * 8 + 0);   // ds_read_b64, bcast/half
        uint2 e1 = *(const uint2*)(pb + kk * 8 + 2);
        uint2 e2 = *(const uint2*)(pb + kk * 8 + 4);
        uint2 e3 = *(const uint2*)(pb + kk * 8 + 6);
        uint d0 = *(const uint*)(rftb + (e0.x + laneByte));
        uint d1 = *(const uint*)(rftb + (e1.x + laneByte));
        uint d2 = *(const uint*)(rftb + (e2.x + laneByte));
        uint d3 = *(const uint*)(rftb + (e3.x + laneByte));
        float W0 = __uint_as_float(e0.y);
        float W1 = __uint_as_float(e1.y);
        float W2 = __uint_as_float(e2.y);
        float W3 = __uint_as_float(e3.y);

        float vlo = W0 * __uint_as_float(d0 << 16);
        vlo = fmaf(W1, __uint_as_float(d1 << 16), vlo);
        vlo = fmaf(W2, __uint_as_float(d2 << 16), vlo);
        vlo = fmaf(W3, __uint_as_float(d3 << 16), vlo);
        float vhi = W0 * __uint_as_float(d0 & 0xffff0000u);
        vhi = fmaf(W1, __uint_as_float(d1 & 0xffff0000u), vhi);
        vhi = fmaf(W2, __uint_as_float(d2 & 0xffff0000u), vhi);
        vhi = fmaf(W3, __uint_as_float(d3 & 0xffff0000u), vhi);
        mLo = fmaxf(mLo, vlo);
        mHi = fmaxf(mHi, vhi);
    }

    uint outw;
    asm("v_cvt_pk_bf16_f32 %0, %1, %2" : "=v"(outw) : "v"(mLo), "v"(mHi));
    // channels 2c (low), 2c+1 (high) of pixel; flow half at cols 64..127
    *(uint*)((char*)xin + (size_t)pix * 256 + 128 + (ln & 31) * 4) = outw;
}

// ---------------------------------------------------------------------------
// conv1: implicit-GEMM MFMA, M=64(o), N=192 (180-px half-row + pad), K=1152.
// Input xin bf16 [p][128]. Output res_t f32 [p][64] (BN+ReLU applied).
// ---------------------------------------------------------------------------
__global__ __launch_bounds__(256) void k_mconv1(const ushort* __restrict__ xin,
                                                const ushort* __restrict__ wA,
                                                const float* __restrict__ g,
                                                const float* __restrict__ b,
                                                const float* __restrict__ mn,
                                                const float* __restrict__ vr,
                                                float* __restrict__ res_t) {
    __shared__ __align__(16) ushort xt[3][194][32];
    int tid = threadIdx.x;
    int h = blockIdx.x >> 1, w0 = (blockIdx.x & 1) * 180;
    int wid = tid >> 6, ln = tid & 63;
    f32x4 acc[4][3];
    #pragma unroll
    for (int m = 0; m < 4; m++)
        #pragma unroll
        for (int nf = 0; nf < 3; nf++) acc[m][nf] = (f32x4){0.f, 0.f, 0.f, 0.f};

    for (int c = 0; c < 4; c++) {
        __syncthreads();
        for (int i = tid; i < 2184; i += 256) {          // 546 slots x 4 quads
            int q = i & 3, s = i >> 2;
            int r = s / 182, pw = s - r * 182;
            int gh = h + r - 1;
            int gw = w0 + pw - 1;
            if (gw < 0) gw += WW;
            if (gw >= WW) gw -= WW;
            int4_ val = {0, 0, 0, 0};
            if ((unsigned)gh < (unsigned)HH)
                val = *(const int4_*)(xin + ((size_t)(gh * WW + gw) * 128 + c * 32 + q * 8));
            *(int4_*)&xt[r][pw][(q ^ (pw & 3)) * 8] = val;
        }
        __syncthreads();
        #pragma unroll
        for (int tap = 0; tap < 9; tap++) {
            int dh = tap / 3, dw = tap % 3;
            short8 aF[4];
            #pragma unroll
            for (int m = 0; m < 4; m++)
                aF[m] = *(const short8*)(wA + (size_t)(((c * 9 + tap) * 4 + m) * 64 + ln) * 8);
            short8 bF[3];
            #pragma unroll
            for (int nf = 0; nf < 3; nf++) {
                int pw = wid * 48 + nf * 16 + (ln & 15) + dw;
                bF[nf] = *(const short8*)&xt[dh][pw][((((ln >> 4) & 3)) ^ (pw & 3)) * 8];
            }
            #pragma unroll
            for (int m = 0; m < 4; m++)
                #pragma unroll
                for (int nf = 0; nf < 3; nf++)
                    acc[m][nf] = __builtin_amdgcn_mfma_f32_16x16x32_bf16(aF[m], bF[nf], acc[m][nf], 0, 0, 0);
        }
    }
    // epilogue: BN + ReLU -> res_t[p][o]
    #pragma unroll
    for (int m = 0; m < 4; m++) {
        #pragma unroll
        for (int reg = 0; reg < 4; reg++) {
            int o = m * 16 + ((ln >> 4) & 3) * 4 + reg;
            float sc = g[o] * rsqrtf(vr[o] + 1e-5f);
            float bi = b[o] - mn[o] * sc;
            #pragma unroll
            for (int nf = 0; nf < 3; nf++) {
                int n = wid * 48 + nf * 16 + (ln & 15);
                if (n < 180) {
                    int P = h * WW + w0 + n;
                    float v = fmaf(acc[m][nf][reg], sc, bi);
                    res_t[(size_t)P * 64 + o] = fmaxf(v, 0.f);
                }
            }
        }
    }
}

// ---------------------------------------------------------------------------
// conv2: same GEMM (K=576) on res_t (f32 -> bf16 staged), BN + channel
// softmax + final out = polar + res*att.
// ---------------------------------------------------------------------------
__global__ __launch_bounds__(256) void k_mconv2(const float* __restrict__ res_t,
                                                const float* __restrict__ polar,
                                                const ushort* __restrict__ wA,
                                                const float* __restrict__ g,
                                                const float* __restrict__ b,
                                                const float* __restrict__ mn,
                                                const float* __restrict__ vr,
                                                float* __restrict__ out) {
    __shared__ __align__(16) ushort xt[3][194][32];
    int tid = threadIdx.x;
    int h = blockIdx.x >> 1, w0 = (blockIdx.x & 1) * 180;
    int wid = tid >> 6, ln = tid & 63;
    f32x4 acc[4][3];
    #pragma unroll
    for (int m = 0; m < 4; m++)
        #pragma unroll
        for (int nf = 0; nf < 3; nf++) acc[m][nf] = (f32x4){0.f, 0.f, 0.f, 0.f};

    for (int c = 0; c < 2; c++) {
        __syncthreads();
        for (int i = tid; i < 2184; i += 256) {
            int q = i & 3, s = i >> 2;
            int r = s / 182, pw = s - r * 182;
            int gh = h + r - 1;
            int gw = w0 + pw - 1;
            if (gw < 0) gw += WW;
            if (gw >= WW) gw -= WW;
            int4_ val = {0, 0, 0, 0};
            if ((unsigned)gh < (unsigned)HH) {
                const float* src = res_t + ((size_t)(gh * WW + gw) * 64 + c * 32 + q * 8);
                f32x4 va = *(const f32x4*)src;
                f32x4 vb = *(const f32x4*)(src + 4);
                uint u0, u1, u2, u3;
                asm("v_cvt_pk_bf16_f32 %0, %1, %2" : "=v"(u0) : "v"(va[0]), "v"(va[1]));
                asm("v_cvt_pk_bf16_f32 %0, %1, %2" : "=v"(u1) : "v"(va[2]), "v"(va[3]));
                asm("v_cvt_pk_bf16_f32 %0, %1, %2" : "=v"(u2) : "v"(vb[0]), "v"(vb[1]));
                asm("v_cvt_pk_bf16_f32 %0, %1, %2" : "=v"(u3) : "v"(vb[2]), "v"(vb[3]));
                val = (int4_){(int)u0, (int)u1, (int)u2, (int)u3};
            }
            *(int4_*)&xt[r][pw][(q ^ (pw & 3)) * 8] = val;
        }
        __syncthreads();
        #pragma unroll
        for (int tap = 0; tap < 9; tap++) {
            int dh = tap / 3, dw = tap % 3;
            short8 aF[4];
            #pragma unroll
            for (int m = 0; m < 4; m++)
                aF[m] = *(const short8*)(wA + (size_t)(((c * 9 + tap) * 4 + m) * 64 + ln) * 8);
            short8 bF[3];
            #pragma unroll
            for (int nf = 0; nf < 3; nf++) {
                int pw = wid * 48 + nf * 16 + (ln & 15) + dw;
                bF[nf] = *(const short8*)&xt[dh][pw][((((ln >> 4) & 3)) ^ (pw & 3)) * 8];
            }
            #pragma unroll
            for (int m = 0; m < 4; m++)
                #pragma unroll
                for (int nf = 0; nf < 3; nf++)
                    acc[m][nf] = __builtin_amdgcn_mfma_f32_16x16x32_bf16(aF[m], bF[nf], acc[m][nf], 0, 0, 0);
        }
    }
    // epilogue: BN -> softmax over 64 channels -> out = polar + res*att
    #pragma unroll
    for (int m = 0; m < 4; m++) {
        #pragma unroll
        for (int reg = 0; reg < 4; reg++) {
            int o = m * 16 + ((ln >> 4) & 3) * 4 + reg;
            float sc = g[o] * rsqrtf(vr[o] + 1e-5f);
            float bi = b[o] - mn[o] * sc;
            #pragma unroll
            for (int nf = 0; nf < 3; nf++)
                acc[m][nf][reg] = fmaf(acc[m][nf][reg], sc, bi);
        }
    }
    #pragma unroll
    for (int nf = 0; nf < 3; nf++) {
        float mx = -3.0e38f;
        #pragma unroll
        for (int m = 0; m < 4; m++)
            #pragma unroll
            for (int reg = 0; reg < 4; reg++) mx = fmaxf(mx, acc[m][nf][reg]);
        mx = fmaxf(mx, __shfl_xor(mx, 16));
        mx = fmaxf(mx, __shfl_xor(mx, 32));
        float s = 0.f;
        #pragma unroll
        for (int m = 0; m < 4; m++)
            #pragma unroll
            for (int reg = 0; reg < 4; reg++) {
                float e = __expf(acc[m][nf][reg] - mx);
                acc[m][nf][reg] = e;
                s += e;
            }
        s += __shfl_xor(s, 16);
        s += __shfl_xor(s, 32);
        float rinv = 1.f / s;
        int n = wid * 48 + nf * 16 + (ln & 15);
        if (n < 180) {
            int P = h * WW + w0 + n;
            #pragma unroll
            for (int m = 0; m < 4; m++)
                #pragma unroll
                for (int reg = 0; reg < 4; reg++) {
                    int o = m * 16 + ((ln >> 4) & 3) * 4 + reg;
                    float att = acc[m][nf][reg] * rinv;
                    out[(size_t)o * NPIX + P] =
                        fmaf(res_t[(size_t)P * 64 + o], att, polar[(size_t)o * NPIX + P]);
                }
        }
    }
}

// ---------------------------------------------------------------------------
extern "C" void kernel_launch(void* const* d_in, const int* in_sizes, int n_in,
                              void* d_out, int out_size, void* d_ws, size_t ws_size,
                              hipStream_t stream) {
    const float* flow  = (const float*)d_in[0];
    const float* polar = (const float*)d_in[1];
    const float* rf    = (const float*)d_in[2];
    const float* fw    = (const float*)d_in[3];
    const float* fg    = (const float*)d_in[4];
    const float* fb    = (const float*)d_in[5];
    const float* fm    = (const float*)d_in[6];
    const float* fv    = (const float*)d_in[7];
    const float* aw    = (const float*)d_in[8];
    const float* ag    = (const float*)d_in[9];
    const float* ab    = (const float*)d_in[10];
    const float* am    = (const float*)d_in[11];
    const float* av    = (const float*)d_in[12];
    float* out = (float*)d_out;

    char* wsb = (char*)d_ws;
    ushort* xin   = (ushort*)wsb;                         // [NPIX][128] bf16 = 44,236,800 B
    ushort* rft   = (ushort*)(wsb + 44236800);            // [RFNPIX][64] bf16 + 128B zero-land
    float*  res_t = (float*)(wsb + 61014272);             // [NPIX][64] f32 = 44,236,800 B
    ushort* wA1   = (ushort*)(wsb + 105251072);           // 147,456 B
    ushort* wA2   = wA1 + 73728;                          // 73,728 B

    k_wprep<<<432, 256, 0, stream>>>(fw, aw, wA1, wA2);
    k_tr<<<NPIX / 64, 256, 0, stream>>>(polar, xin, NPIX, 128);
    k_tr<<<RFNPIX / 64, 256, 0, stream>>>(rf, rft, RFNPIX, 64);
    k_zero<<<1, 64, 0, stream>>>((uint*)rft);
    k_sample<<<NPIX / 8, 256, 0, stream>>>(flow, (const char*)rft, xin);
    k_mconv1<<<960, 256, 0, stream>>>(xin, wA1, fg, fb, fm, fv, res_t);
    k_mconv2<<<960, 256, 0, stream>>>(res_t, polar, wA2, ag, ab, am, av, out);
}

// Round 5
// 440.677 us; speedup vs baseline: 2.9197x; 1.0356x over previous
//
#include <hip/hip_runtime.h>
#include <math.h>

#define CCH 64
#define HH 480
#define WW 360
#define KK 32
#define HR 64
#define WR 2048
#define NPIX (HH*WW)            // 172800
#define RFNPIX (HR*WR)          // 131072
#define ZOFF 16777216u          // byte offset of zero line in rfT16
#define NEGOFF 16777344u        // byte offset of -3.4e38 sentinel line

typedef __attribute__((ext_vector_type(8))) short short8;
typedef __attribute__((ext_vector_type(4))) float f32x4;
typedef __attribute__((ext_vector_type(4))) int  int4_;

__device__ __forceinline__ ushort f2bf(float f) {        // RTN f32->bf16
    uint u = __float_as_uint(f);
    return (ushort)((u + 0x7fffu + ((u >> 16) & 1u)) >> 16);
}

// ---------------------------------------------------------------------------
// Weight prep: pack conv weights into MFMA A-fragment order, bf16.
// ---------------------------------------------------------------------------
__global__ __launch_bounds__(256) void k_wprep(const float* __restrict__ fw,
                                               const float* __restrict__ aw,
                                               ushort* __restrict__ wA1,
                                               ushort* __restrict__ wA2) {
    int t = blockIdx.x * 256 + threadIdx.x;
    if (t < 73728) {                                   // conv1: 4 chunks (128 ci)
        int j = t & 7, ln = (t >> 3) & 63, Mf = (t >> 9) & 3, rem = t >> 11;
        int tap = rem % 9, c = rem / 9;
        int o = Mf * 16 + (ln & 15);
        int ci = c * 32 + ((ln >> 4) & 3) * 8 + j;
        wA1[t] = f2bf(fw[(o * 128 + ci) * 9 + tap]);
    } else if (t < 73728 + 36864) {                    // conv2: 2 chunks (64 ci)
        int i = t - 73728;
        int j = i & 7, ln = (i >> 3) & 63, Mf = (i >> 9) & 3, rem = i >> 11;
        int tap = rem % 9, c = rem / 9;
        int o = Mf * 16 + (ln & 15);
        int ci = c * 32 + ((ln >> 4) & 3) * 8 + j;
        wA2[i] = f2bf(aw[(o * 64 + ci) * 9 + tap]);
    }
}

// ---------------------------------------------------------------------------
// Transpose f32 [64][npix] -> bf16 channel-last [npix][rowShorts] (cols 0..63)
// ---------------------------------------------------------------------------
__global__ __launch_bounds__(256) void k_tr(const float* __restrict__ src,
                                            ushort* __restrict__ dst,
                                            int npix, int rowShorts) {
    __shared__ float lds[64][65];
    int t = threadIdx.x;
    int pix0 = blockIdx.x * 64;
    int lx = t & 63, ty = t >> 6;
    #pragma unroll
    for (int cc = 0; cc < 64; cc += 4) {
        int c = cc + ty;
        lds[c][lx] = src[(size_t)c * npix + pix0 + lx];
    }
    __syncthreads();
    int cp = t & 31, po = t >> 5;        // cp = channel pair, po = pixel offset
    #pragma unroll
    for (int pl = po; pl < 64; pl += 8) {
        uint u = (uint)f2bf(lds[2 * cp][pl]) | ((uint)f2bf(lds[2 * cp + 1][pl]) << 16);
        *(uint*)(dst + (size_t)(pix0 + pl) * rowShorts + cp * 2) = u;
    }
}

// zero line at ZOFF, -3.4e38 (bf16 pair pattern) line at NEGOFF
__global__ void k_zero(uint* __restrict__ rft32) {
    int t = threadIdx.x;
    if (t < 32)       rft32[(ZOFF >> 2) + t] = 0;
    else if (t < 64)  rft32[(NEGOFF >> 2) + (t - 32)] = 0xFF7FFF7Fu;
}

// ---------------------------------------------------------------------------
// Flow sampling v4: 2 pixels per wave; per-lane prep of one (pixel,k) ->
// 4 corner byte-offsets + 4 weights in LDS, counting-sorted per half-wave by
// slice id (sid = clamped_y0>>4; slice s = table rows [16s,16s+16], 4.25 MB
// ~= one XCD L2). Gather loop runs 4 passes over the sorted buckets so
// concurrent blocks keep one slice L2-hot. Wave trip per pass =
// max(cntA,cntB); surplus iters of the shorter half read a dummy entry
// (w00=1 at NEGOFF sentinel = -3.4e38, neutral in max, L1-resident).
// ---------------------------------------------------------------------------
__global__ __launch_bounds__(256) void k_sample(const float* __restrict__ flow,
                                                const char* __restrict__ rftb,
                                                ushort* __restrict__ xin) {
    __shared__ __align__(16) uint pbuf[4][2][33][8];   // [wave][half][entry][(off,w)x4]
    int tid = threadIdx.x;
    int ln = tid & 63;
    int wid = tid >> 6;
    int half = ln >> 5;
    int gwave = blockIdx.x * 4 + wid;

    // ---- prep (per-lane: one (pixel,k)) ----
    int k = ln & 31;
    int pix = gwave * 2 + half;
    const float* fp = flow + (size_t)pix * 64 + 2 * k;
    float gy = fp[0], gx = fp[1];
    float ix = fmaf(gx, 1024.f, 1023.5f);
    float iy = fmaf(gy, 32.f, 31.5f);
    float xf = floorf(ix), yf = floorf(iy);
    float wx = ix - xf, wy = iy - yf;
    int x0 = (int)xf, y0 = (int)yf;
    bool xv0 = (unsigned)x0 < (unsigned)WR;
    bool xv1 = (unsigned)(x0 + 1) < (unsigned)WR;
    bool yv0 = (unsigned)y0 < (unsigned)HR;
    bool yv1 = (unsigned)(y0 + 1) < (unsigned)HR;
    int xc0 = x0 < 0 ? 0 : x0;
    int xc1 = x0 + 1 > WR - 1 ? WR - 1 : x0 + 1;
    int yc0 = y0 < 0 ? 0 : y0;
    int yc1 = y0 + 1 > HR - 1 ? HR - 1 : y0 + 1;
    uint o00 = (xv0 && yv0) ? (uint)(((yc0 << 11) + xc0) << 7) : ZOFF;
    uint o01 = (xv1 && yv0) ? (uint)(((yc0 << 11) + xc1) << 7) : ZOFF;
    uint o10 = (xv0 && yv1) ? (uint)(((yc1 << 11) + xc0) << 7) : ZOFF;
    uint o11 = (xv1 && yv1) ? (uint)(((yc1 << 11) + xc1) << 7) : ZOFF;
    float w00 = (1.f - wy) * (1.f - wx);
    float w01 = (1.f - wy) * wx;
    float w10 = wy * (1.f - wx);
    float w11 = wy * wx;

    // ---- counting sort by slice id within each half-wave ----
    int sid = yc0 >> 4;                                  // 0..3
    unsigned long long b0 = __ballot(sid == 0);
    unsigned long long b1 = __ballot(sid == 1);
    unsigned long long b2 = __ballot(sid == 2);
    unsigned long long b3 = __ballot(sid == 3);
    unsigned long long hm = half ? 0xFFFFFFFF00000000ull : 0x00000000FFFFFFFFull;
    int c0 = __popcll(b0 & hm), c1 = __popcll(b1 & hm);
    int c2 = __popcll(b2 & hm), c3 = __popcll(b3 & hm);
    int st1 = c0, st2 = c0 + c1, st3 = c0 + c1 + c2;
    unsigned long long mysel = (sid == 0) ? b0 : (sid == 1) ? b1 : (sid == 2) ? b2 : b3;
    unsigned long long lower = (1ull << ln) - 1ull;
    int rank = __popcll(mysel & hm & lower);
    int mystart = (sid == 0) ? 0 : (sid == 1) ? st1 : (sid == 2) ? st2 : st3;
    int pos = mystart + rank;
    *(int4_*)&pbuf[wid][half][pos][0] =
        (int4_){(int)o00, __float_as_int(w00), (int)o01, __float_as_int(w01)};
    *(int4_*)&pbuf[wid][half][pos][4] =
        (int4_){(int)o10, __float_as_int(w10), (int)o11, __float_as_int(w11)};
    if ((ln & 31) == 0) {                                // dummy entry at pos 32
        *(int4_*)&pbuf[wid][half][32][0] =
            (int4_){(int)NEGOFF, __float_as_int(1.0f), (int)ZOFF, 0};
        *(int4_*)&pbuf[wid][half][32][4] = (int4_){(int)ZOFF, 0, (int)ZOFF, 0};
    }
    __syncthreads();

    uint laneByte = (uint)((ln & 31) * 4);
    const uint* pb = &pbuf[wid][half][0][0];
    float mLo = -3.0e38f, mHi = -3.0e38f;
    int cnts[4]  = {c0, c1, c2, c3};
    int starts[4] = {0, st1, st2, st3};

    // ---- gather: 4 slice passes over sorted buckets ----
    #pragma unroll
    for (int s = 0; s < 4; s++) {
        int myCnt = cnts[s];
        int myStart = starts[s];
        int cA = __builtin_amdgcn_readlane(myCnt, 0);
        int cB = __builtin_amdgcn_readlane(myCnt, 32);
        int trip = cA > cB ? cA : cB;
        for (int i = 0; i < trip; i++) {
            int idx = (i < myCnt) ? (myStart + i) : 32;
            const uint* e = pb + idx * 8;
            uint2 e0 = *(const uint2*)(e + 0);           // ds_read_b64, bcast/half
            uint2 e1 = *(const uint2*)(e + 2);
            uint2 e2 = *(const uint2*)(e + 4);
            uint2 e3 = *(const uint2*)(e + 6);
            uint d0 = *(const uint*)(rftb + (e0.x + laneByte));
            uint d1 = *(const uint*)(rftb + (e1.x + laneByte));
            uint d2 = *(const uint*)(rftb + (e2.x + laneByte));
            uint d3 = *(const uint*)(rftb + (e3.x + laneByte));
            float W0 = __uint_as_float(e0.y);
            float W1 = __uint_as_float(e1.y);
            float W2 = __uint_as_float(e2.y);
            float W3 = __uint_as_float(e3.y);

            float vlo = W0 * __uint_as_float(d0 << 16);
            vlo = fmaf(W1, __uint_as_float(d1 << 16), vlo);
            vlo = fmaf(W2, __uint_as_float(d2 << 16), vlo);
            vlo = fmaf(W3, __uint_as_float(d3 << 16), vlo);
            float vhi = W0 * __uint_as_float(d0 & 0xffff0000u);
            vhi = fmaf(W1, __uint_as_float(d1 & 0xffff0000u), vhi);
            vhi = fmaf(W2, __uint_as_float(d2 & 0xffff0000u), vhi);
            vhi = fmaf(W3, __uint_as_float(d3 & 0xffff0000u), vhi);
            mLo = fmaxf(mLo, vlo);
            mHi = fmaxf(mHi, vhi);
        }
    }

    uint outw;
    asm("v_cvt_pk_bf16_f32 %0, %1, %2" : "=v"(outw) : "v"(mLo), "v"(mHi));
    *(uint*)((char*)xin + (size_t)pix * 256 + 128 + (ln & 31) * 4) = outw;
}

// ---------------------------------------------------------------------------
// conv1: implicit-GEMM MFMA, M=64(o), N=192 (180-px half-row + pad), K=1152.
// Input xin bf16 [p][128]. Output res_t f32 [p][64] (BN+ReLU applied).
// ---------------------------------------------------------------------------
__global__ __launch_bounds__(256) void k_mconv1(const ushort* __restrict__ xin,
                                                const ushort* __restrict__ wA,
                                                const float* __restrict__ g,
                                                const float* __restrict__ b,
                                                const float* __restrict__ mn,
                                                const float* __restrict__ vr,
                                                float* __restrict__ res_t) {
    __shared__ __align__(16) ushort xt[3][194][32];
    int tid = threadIdx.x;
    int h = blockIdx.x >> 1, w0 = (blockIdx.x & 1) * 180;
    int wid = tid >> 6, ln = tid & 63;
    f32x4 acc[4][3];
    #pragma unroll
    for (int m = 0; m < 4; m++)
        #pragma unroll
        for (int nf = 0; nf < 3; nf++) acc[m][nf] = (f32x4){0.f, 0.f, 0.f, 0.f};

    for (int c = 0; c < 4; c++) {
        __syncthreads();
        for (int i = tid; i < 2184; i += 256) {          // 546 slots x 4 quads
            int q = i & 3, s = i >> 2;
            int r = s / 182, pw = s - r * 182;
            int gh = h + r - 1;
            int gw = w0 + pw - 1;
            if (gw < 0) gw += WW;
            if (gw >= WW) gw -= WW;
            int4_ val = {0, 0, 0, 0};
            if ((unsigned)gh < (unsigned)HH)
                val = *(const int4_*)(xin + ((size_t)(gh * WW + gw) * 128 + c * 32 + q * 8));
            *(int4_*)&xt[r][pw][(q ^ (pw & 3)) * 8] = val;
        }
        __syncthreads();
        #pragma unroll
        for (int tap = 0; tap < 9; tap++) {
            int dh = tap / 3, dw = tap % 3;
            short8 aF[4];
            #pragma unroll
            for (int m = 0; m < 4; m++)
                aF[m] = *(const short8*)(wA + (size_t)(((c * 9 + tap) * 4 + m) * 64 + ln) * 8);
            short8 bF[3];
            #pragma unroll
            for (int nf = 0; nf < 3; nf++) {
                int pw = wid * 48 + nf * 16 + (ln & 15) + dw;
                bF[nf] = *(const short8*)&xt[dh][pw][((((ln >> 4) & 3)) ^ (pw & 3)) * 8];
            }
            #pragma unroll
            for (int m = 0; m < 4; m++)
                #pragma unroll
                for (int nf = 0; nf < 3; nf++)
                    acc[m][nf] = __builtin_amdgcn_mfma_f32_16x16x32_bf16(aF[m], bF[nf], acc[m][nf], 0, 0, 0);
        }
    }
    // epilogue: BN + ReLU -> res_t[p][o]
    #pragma unroll
    for (int m = 0; m < 4; m++) {
        #pragma unroll
        for (int reg = 0; reg < 4; reg++) {
            int o = m * 16 + ((ln >> 4) & 3) * 4 + reg;
            float sc = g[o] * rsqrtf(vr[o] + 1e-5f);
            float bi = b[o] - mn[o] * sc;
            #pragma unroll
            for (int nf = 0; nf < 3; nf++) {
                int n = wid * 48 + nf * 16 + (ln & 15);
                if (n < 180) {
                    int P = h * WW + w0 + n;
                    float v = fmaf(acc[m][nf][reg], sc, bi);
                    res_t[(size_t)P * 64 + o] = fmaxf(v, 0.f);
                }
            }
        }
    }
}

// ---------------------------------------------------------------------------
// conv2: same GEMM (K=576) on res_t (f32 -> bf16 staged), BN + channel
// softmax + final out = polar + res*att.
// ---------------------------------------------------------------------------
__global__ __launch_bounds__(256) void k_mconv2(const float* __restrict__ res_t,
                                                const float* __restrict__ polar,
                                                const ushort* __restrict__ wA,
                                                const float* __restrict__ g,
                                                const float* __restrict__ b,
                                                const float* __restrict__ mn,
                                                const float* __restrict__ vr,
                                                float* __restrict__ out) {
    __shared__ __align__(16) ushort xt[3][194][32];
    int tid = threadIdx.x;
    int h = blockIdx.x >> 1, w0 = (blockIdx.x & 1) * 180;
    int wid = tid >> 6, ln = tid & 63;
    f32x4 acc[4][3];
    #pragma unroll
    for (int m = 0; m < 4; m++)
        #pragma unroll
        for (int nf = 0; nf < 3; nf++) acc[m][nf] = (f32x4){0.f, 0.f, 0.f, 0.f};

    for (int c = 0; c < 2; c++) {
        __syncthreads();
        for (int i = tid; i < 2184; i += 256) {
            int q = i & 3, s = i >> 2;
            int r = s / 182, pw = s - r * 182;
            int gh = h + r - 1;
            int gw = w0 + pw - 1;
            if (gw < 0) gw += WW;
            if (gw >= WW) gw -= WW;
            int4_ val = {0, 0, 0, 0};
            if ((unsigned)gh < (unsigned)HH) {
                const float* src = res_t + ((size_t)(gh * WW + gw) * 64 + c * 32 + q * 8);
                f32x4 va = *(const f32x4*)src;
                f32x4 vb = *(const f32x4*)(src + 4);
                uint u0, u1, u2, u3;
                asm("v_cvt_pk_bf16_f32 %0, %1, %2" : "=v"(u0) : "v"(va[0]), "v"(va[1]));
                asm("v_cvt_pk_bf16_f32 %0, %1, %2" : "=v"(u1) : "v"(va[2]), "v"(va[3]));
                asm("v_cvt_pk_bf16_f32 %0, %1, %2" : "=v"(u2) : "v"(vb[0]), "v"(vb[1]));
                asm("v_cvt_pk_bf16_f32 %0, %1, %2" : "=v"(u3) : "v"(vb[2]), "v"(vb[3]));
                val = (int4_){(int)u0, (int)u1, (int)u2, (int)u3};
            }
            *(int4_*)&xt[r][pw][(q ^ (pw & 3)) * 8] = val;
        }
        __syncthreads();
        #pragma unroll
        for (int tap = 0; tap < 9; tap++) {
            int dh = tap / 3, dw = tap % 3;
            short8 aF[4];
            #pragma unroll
            for (int m = 0; m < 4; m++)
                aF[m] = *(const short8*)(wA + (size_t)(((c * 9 + tap) * 4 + m) * 64 + ln) * 8);
            short8 bF[3];
            #pragma unroll
            for (int nf = 0; nf < 3; nf++) {
                int pw = wid * 48 + nf * 16 + (ln & 15) + dw;
                bF[nf] = *(const short8*)&xt[dh][pw][((((ln >> 4) & 3)) ^ (pw & 3)) * 8];
            }
            #pragma unroll
            for (int m = 0; m < 4; m++)
                #pragma unroll
                for (int nf = 0; nf < 3; nf++)
                    acc[m][nf] = __builtin_amdgcn_mfma_f32_16x16x32_bf16(aF[m], bF[nf], acc[m][nf], 0, 0, 0);
        }
    }
    // epilogue: BN -> softmax over 64 channels -> out = polar + res*att
    #pragma unroll
    for (int m = 0; m < 4; m++) {
        #pragma unroll
        for (int reg = 0; reg < 4; reg++) {
            int o = m * 16 + ((ln >> 4) & 3) * 4 + reg;
            float sc = g[o] * rsqrtf(vr[o] + 1e-5f);
            float bi = b[o] - mn[o] * sc;
            #pragma unroll
            for (int nf = 0; nf < 3; nf++)
                acc[m][nf][reg] = fmaf(acc[m][nf][reg], sc, bi);
        }
    }
    #pragma unroll
    for (int nf = 0; nf < 3; nf++) {
        float mx = -3.0e38f;
        #pragma unroll
        for (int m = 0; m < 4; m++)
            #pragma unroll
            for (int reg = 0; reg < 4; reg++) mx = fmaxf(mx, acc[m][nf][reg]);
        mx = fmaxf(mx, __shfl_xor(mx, 16));
        mx = fmaxf(mx, __shfl_xor(mx, 32));
        float s = 0.f;
        #pragma unroll
        for (int m = 0; m < 4; m++)
            #pragma unroll
            for (int reg = 0; reg < 4; reg++) {
                float e = __expf(acc[m][nf][reg] - mx);
                acc[m][nf][reg] = e;
                s += e;
            }
        s += __shfl_xor(s, 16);
        s += __shfl_xor(s, 32);
        float rinv = 1.f / s;
        int n = wid * 48 + nf * 16 + (ln & 15);
        if (n < 180) {
            int P = h * WW + w0 + n;
            #pragma unroll
            for (int m = 0; m < 4; m++)
                #pragma unroll
                for (int reg = 0; reg < 4; reg++) {
                    int o = m * 16 + ((ln >> 4) & 3) * 4 + reg;
                    float att = acc[m][nf][reg] * rinv;
                    out[(size_t)o * NPIX + P] =
                        fmaf(res_t[(size_t)P * 64 + o], att, polar[(size_t)o * NPIX + P]);
                }
        }
    }
}

// ---------------------------------------------------------------------------
extern "C" void kernel_launch(void* const* d_in, const int* in_sizes, int n_in,
                              void* d_out, int out_size, void* d_ws, size_t ws_size,
                              hipStream_t stream) {
    const float* flow  = (const float*)d_in[0];
    const float* polar = (const float*)d_in[1];
    const float* rf    = (const float*)d_in[2];
    const float* fw    = (const float*)d_in[3];
    const float* fg    = (const float*)d_in[4];
    const float* fb    = (const float*)d_in[5];
    const float* fm    = (const float*)d_in[6];
    const float* fv    = (const float*)d_in[7];
    const float* aw    = (const float*)d_in[8];
    const float* ag    = (const float*)d_in[9];
    const float* ab    = (const float*)d_in[10];
    const float* am    = (const float*)d_in[11];
    const float* av    = (const float*)d_in[12];
    float* out = (float*)d_out;

    char* wsb = (char*)d_ws;
    ushort* xin   = (ushort*)wsb;                         // [NPIX][128] bf16 = 44,236,800 B
    ushort* rft   = (ushort*)(wsb + 44236800);            // [RFNPIX][64] bf16 + 256B sentinel lines
    float*  res_t = (float*)(wsb + 61014272);             // [NPIX][64] f32 = 44,236,800 B
    ushort* wA1   = (ushort*)(wsb + 105251072);           // 147,456 B
    ushort* wA2   = wA1 + 73728;                          // 73,728 B

    k_wprep<<<432, 256, 0, stream>>>(fw, aw, wA1, wA2);
    k_tr<<<NPIX / 64, 256, 0, stream>>>(polar, xin, NPIX, 128);
    k_tr<<<RFNPIX / 64, 256, 0, stream>>>(rf, rft, RFNPIX, 64);
    k_zero<<<1, 64, 0, stream>>>((uint*)rft);
    k_sample<<<NPIX / 8, 256, 0, stream>>>(flow, (const char*)rft, xin);
    k_mconv1<<<960, 256, 0, stream>>>(xin, wA1, fg, fb, fm, fv, res_t);
    k_mconv2<<<960, 256, 0, stream>>>(res_t, polar, wA2, ag, ab, am, av, out);
}

// Round 7
// 430.844 us; speedup vs baseline: 2.9863x; 1.0228x over previous
//
#include <hip/hip_runtime.h>
#include <math.h>

#define CCH 64
#define HH 480
#define WW 360
#define KK 32
#define HR 64
#define WR 2048
#define NPIX (HH*WW)            // 172800
#define RFNPIX (HR*WR)          // 131072
#define ZOFF 16777216u          // byte offset of zero line in rfT16
#define NEGOFF 16777344u        // byte offset of -3.4e38 sentinel line

typedef __attribute__((ext_vector_type(8))) short short8;
typedef __attribute__((ext_vector_type(4))) float f32x4;
typedef __attribute__((ext_vector_type(4))) int  int4_;

__device__ __forceinline__ ushort f2bf(float f) {        // RTN f32->bf16
    uint u = __float_as_uint(f);
    return (ushort)((u + 0x7fffu + ((u >> 16) & 1u)) >> 16);
}

// ---------------------------------------------------------------------------
// Weight prep: pack conv weights into MFMA A-fragment order, bf16.
// ---------------------------------------------------------------------------
__global__ __launch_bounds__(256) void k_wprep(const float* __restrict__ fw,
                                               const float* __restrict__ aw,
                                               ushort* __restrict__ wA1,
                                               ushort* __restrict__ wA2) {
    int t = blockIdx.x * 256 + threadIdx.x;
    if (t < 73728) {                                   // conv1: 4 chunks (128 ci)
        int j = t & 7, ln = (t >> 3) & 63, Mf = (t >> 9) & 3, rem = t >> 11;
        int tap = rem % 9, c = rem / 9;
        int o = Mf * 16 + (ln & 15);
        int ci = c * 32 + ((ln >> 4) & 3) * 8 + j;
        wA1[t] = f2bf(fw[(o * 128 + ci) * 9 + tap]);
    } else if (t < 73728 + 36864) {                    // conv2: 2 chunks (64 ci)
        int i = t - 73728;
        int j = i & 7, ln = (i >> 3) & 63, Mf = (i >> 9) & 3, rem = i >> 11;
        int tap = rem % 9, c = rem / 9;
        int o = Mf * 16 + (ln & 15);
        int ci = c * 32 + ((ln >> 4) & 3) * 8 + j;
        wA2[i] = f2bf(aw[(o * 64 + ci) * 9 + tap]);
    }
}

// ---------------------------------------------------------------------------
// Transpose f32 [64][npix] -> bf16 channel-last [npix][rowShorts] (cols 0..63)
// ---------------------------------------------------------------------------
__global__ __launch_bounds__(256) void k_tr(const float* __restrict__ src,
                                            ushort* __restrict__ dst,
                                            int npix, int rowShorts) {
    __shared__ float lds[64][65];
    int t = threadIdx.x;
    int pix0 = blockIdx.x * 64;
    int lx = t & 63, ty = t >> 6;
    #pragma unroll
    for (int cc = 0; cc < 64; cc += 4) {
        int c = cc + ty;
        lds[c][lx] = src[(size_t)c * npix + pix0 + lx];
    }
    __syncthreads();
    int cp = t & 31, po = t >> 5;        // cp = channel pair, po = pixel offset
    #pragma unroll
    for (int pl = po; pl < 64; pl += 8) {
        uint u = (uint)f2bf(lds[2 * cp][pl]) | ((uint)f2bf(lds[2 * cp + 1][pl]) << 16);
        *(uint*)(dst + (size_t)(pix0 + pl) * rowShorts + cp * 2) = u;
    }
}

// zero line at ZOFF, -3.4e38 (bf16 pair pattern) line at NEGOFF
__global__ void k_zero(uint* __restrict__ rft32) {
    int t = threadIdx.x;
    if (t < 32)       rft32[(ZOFF >> 2) + t] = 0;
    else if (t < 64)  rft32[(NEGOFF >> 2) + (t - 32)] = 0xFF7FFF7Fu;
}

// ---------------------------------------------------------------------------
// Flow sampling v5: 2 pixels per wave; per-lane prep of one (pixel,k) ->
// 4 corner byte-offsets + 4 weights in LDS, counting-sorted per half-wave by
// slice id (sid = clamped_y0>>3; slice s = table rows [8s, 8s+8], 9 rows =
// 2.25 MB << 4 MB per-XCD L2 -- v4's 17-row/4.25MB slice OVERFLOWED the L2,
// which is why it only gained 6%). Gather loop runs 8 passes over sorted
// buckets so concurrent blocks keep one slice L2-hot per XCD. Wave trip per
// pass = max(cntA,cntB); surplus iters of the shorter half read a dummy
// entry (w00=1 at NEGOFF sentinel = -3.4e38, neutral in max, L1-resident).
// ---------------------------------------------------------------------------
__global__ __launch_bounds__(256) void k_sample(const float* __restrict__ flow,
                                                const char* __restrict__ rftb,
                                                ushort* __restrict__ xin) {
    __shared__ __align__(16) uint pbuf[4][2][33][8];   // [wave][half][entry][(off,w)x4]
    int tid = threadIdx.x;
    int ln = tid & 63;
    int wid = tid >> 6;
    int half = ln >> 5;
    int gwave = blockIdx.x * 4 + wid;

    // ---- prep (per-lane: one (pixel,k)) ----
    int k = ln & 31;
    int pix = gwave * 2 + half;
    const float* fp = flow + (size_t)pix * 64 + 2 * k;
    float gy = fp[0], gx = fp[1];
    float ix = fmaf(gx, 1024.f, 1023.5f);
    float iy = fmaf(gy, 32.f, 31.5f);
    float xf = floorf(ix), yf = floorf(iy);
    float wx = ix - xf, wy = iy - yf;
    int x0 = (int)xf, y0 = (int)yf;
    bool xv0 = (unsigned)x0 < (unsigned)WR;
    bool xv1 = (unsigned)(x0 + 1) < (unsigned)WR;
    bool yv0 = (unsigned)y0 < (unsigned)HR;
    bool yv1 = (unsigned)(y0 + 1) < (unsigned)HR;
    int xc0 = x0 < 0 ? 0 : x0;
    int xc1 = x0 + 1 > WR - 1 ? WR - 1 : x0 + 1;
    int yc0 = y0 < 0 ? 0 : y0;
    int yc1 = y0 + 1 > HR - 1 ? HR - 1 : y0 + 1;
    uint o00 = (xv0 && yv0) ? (uint)(((yc0 << 11) + xc0) << 7) : ZOFF;
    uint o01 = (xv1 && yv0) ? (uint)(((yc0 << 11) + xc1) << 7) : ZOFF;
    uint o10 = (xv0 && yv1) ? (uint)(((yc1 << 11) + xc0) << 7) : ZOFF;
    uint o11 = (xv1 && yv1) ? (uint)(((yc1 << 11) + xc1) << 7) : ZOFF;
    float w00 = (1.f - wy) * (1.f - wx);
    float w01 = (1.f - wy) * wx;
    float w10 = wy * (1.f - wx);
    float w11 = wy * wx;

    // ---- counting sort by slice id (8 buckets) within each half-wave ----
    int sid = yc0 >> 3;                                  // 0..7
    unsigned long long hm = half ? 0xFFFFFFFF00000000ull : 0x00000000FFFFFFFFull;
    unsigned long long lower = (1ull << ln) - 1ull;
    int cnts[8], starts[8];
    int mystart = 0, rank = 0, acc = 0;
    #pragma unroll
    for (int s = 0; s < 8; s++) {
        unsigned long long bal = __ballot(sid == s);
        int c = __popcll(bal & hm);
        cnts[s] = c;
        starts[s] = acc;
        if (sid == s) {
            mystart = acc;
            rank = __popcll(bal & hm & lower);
        }
        acc += c;
    }
    int pos = mystart + rank;
    *(int4_*)&pbuf[wid][half][pos][0] =
        (int4_){(int)o00, __float_as_int(w00), (int)o01, __float_as_int(w01)};
    *(int4_*)&pbuf[wid][half][pos][4] =
        (int4_){(int)o10, __float_as_int(w10), (int)o11, __float_as_int(w11)};
    if ((ln & 31) == 0) {                                // dummy entry at pos 32
        *(int4_*)&pbuf[wid][half][32][0] =
            (int4_){(int)NEGOFF, __float_as_int(1.0f), (int)ZOFF, 0};
        *(int4_*)&pbuf[wid][half][32][4] = (int4_){(int)ZOFF, 0, (int)ZOFF, 0};
    }
    __syncthreads();

    uint laneByte = (uint)((ln & 31) * 4);
    const uint* pb = &pbuf[wid][half][0][0];
    float mLo = -3.0e38f, mHi = -3.0e38f;

    // ---- gather: 8 slice passes over sorted buckets ----
    #pragma unroll
    for (int s = 0; s < 8; s++) {
        int myCnt = cnts[s];
        int myStart = starts[s];
        int cA = __builtin_amdgcn_readlane(myCnt, 0);
        int cB = __builtin_amdgcn_readlane(myCnt, 32);
        int trip = cA > cB ? cA : cB;
        for (int i = 0; i < trip; i++) {
            int idx = (i < myCnt) ? (myStart + i) : 32;
            const uint* e = pb + idx * 8;
            uint2 e0 = *(const uint2*)(e + 0);           // ds_read_b64, bcast/half
            uint2 e1 = *(const uint2*)(e + 2);
            uint2 e2 = *(const uint2*)(e + 4);
            uint2 e3 = *(const uint2*)(e + 6);
            uint d0 = *(const uint*)(rftb + (e0.x + laneByte));
            uint d1 = *(const uint*)(rftb + (e1.x + laneByte));
            uint d2 = *(const uint*)(rftb + (e2.x + laneByte));
            uint d3 = *(const uint*)(rftb + (e3.x + laneByte));
            float W0 = __uint_as_float(e0.y);
            float W1 = __uint_as_float(e1.y);
            float W2 = __uint_as_float(e2.y);
            float W3 = __uint_as_float(e3.y);

            float vlo = W0 * __uint_as_float(d0 << 16);
            vlo = fmaf(W1, __uint_as_float(d1 << 16), vlo);
            vlo = fmaf(W2, __uint_as_float(d2 << 16), vlo);
            vlo = fmaf(W3, __uint_as_float(d3 << 16), vlo);
            float vhi = W0 * __uint_as_float(d0 & 0xffff0000u);
            vhi = fmaf(W1, __uint_as_float(d1 & 0xffff0000u), vhi);
            vhi = fmaf(W2, __uint_as_float(d2 & 0xffff0000u), vhi);
            vhi = fmaf(W3, __uint_as_float(d3 & 0xffff0000u), vhi);
            mLo = fmaxf(mLo, vlo);
            mHi = fmaxf(mHi, vhi);
        }
    }

    uint outw;
    asm("v_cvt_pk_bf16_f32 %0, %1, %2" : "=v"(outw) : "v"(mLo), "v"(mHi));
    *(uint*)((char*)xin + (size_t)pix * 256 + 128 + (ln & 31) * 4) = outw;
}

// ---------------------------------------------------------------------------
// conv1: implicit-GEMM MFMA, M=64(o), N=192 (180-px half-row + pad), K=1152.
// Input xin bf16 [p][128]. Output res_t f32 [p][64] (BN+ReLU applied).
// ---------------------------------------------------------------------------
__global__ __launch_bounds__(256) void k_mconv1(const ushort* __restrict__ xin,
                                                const ushort* __restrict__ wA,
                                                const float* __restrict__ g,
                                                const float* __restrict__ b,
                                                const float* __restrict__ mn,
                                                const float* __restrict__ vr,
                                                float* __restrict__ res_t) {
    __shared__ __align__(16) ushort xt[3][194][32];
    int tid = threadIdx.x;
    int h = blockIdx.x >> 1, w0 = (blockIdx.x & 1) * 180;
    int wid = tid >> 6, ln = tid & 63;
    f32x4 acc[4][3];
    #pragma unroll
    for (int m = 0; m < 4; m++)
        #pragma unroll
        for (int nf = 0; nf < 3; nf++) acc[m][nf] = (f32x4){0.f, 0.f, 0.f, 0.f};

    for (int c = 0; c < 4; c++) {
        __syncthreads();
        for (int i = tid; i < 2184; i += 256) {          // 546 slots x 4 quads
            int q = i & 3, s = i >> 2;
            int r = s / 182, pw = s - r * 182;
            int gh = h + r - 1;
            int gw = w0 + pw - 1;
            if (gw < 0) gw += WW;
            if (gw >= WW) gw -= WW;
            int4_ val = {0, 0, 0, 0};
            if ((unsigned)gh < (unsigned)HH)
                val = *(const int4_*)(xin + ((size_t)(gh * WW + gw) * 128 + c * 32 + q * 8));
            *(int4_*)&xt[r][pw][(q ^ (pw & 3)) * 8] = val;
        }
        __syncthreads();
        #pragma unroll
        for (int tap = 0; tap < 9; tap++) {
            int dh = tap / 3, dw = tap % 3;
            short8 aF[4];
            #pragma unroll
            for (int m = 0; m < 4; m++)
                aF[m] = *(const short8*)(wA + (size_t)(((c * 9 + tap) * 4 + m) * 64 + ln) * 8);
            short8 bF[3];
            #pragma unroll
            for (int nf = 0; nf < 3; nf++) {
                int pw = wid * 48 + nf * 16 + (ln & 15) + dw;
                bF[nf] = *(const short8*)&xt[dh][pw][((((ln >> 4) & 3)) ^ (pw & 3)) * 8];
            }
            #pragma unroll
            for (int m = 0; m < 4; m++)
                #pragma unroll
                for (int nf = 0; nf < 3; nf++)
                    acc[m][nf] = __builtin_amdgcn_mfma_f32_16x16x32_bf16(aF[m], bF[nf], acc[m][nf], 0, 0, 0);
        }
    }
    // epilogue: BN + ReLU -> res_t[p][o]
    #pragma unroll
    for (int m = 0; m < 4; m++) {
        #pragma unroll
        for (int reg = 0; reg < 4; reg++) {
            int o = m * 16 + ((ln >> 4) & 3) * 4 + reg;
            float sc = g[o] * rsqrtf(vr[o] + 1e-5f);
            float bi = b[o] - mn[o] * sc;
            #pragma unroll
            for (int nf = 0; nf < 3; nf++) {
                int n = wid * 48 + nf * 16 + (ln & 15);
                if (n < 180) {
                    int P = h * WW + w0 + n;
                    float v = fmaf(acc[m][nf][reg], sc, bi);
                    res_t[(size_t)P * 64 + o] = fmaxf(v, 0.f);
                }
            }
        }
    }
}

// ---------------------------------------------------------------------------
// conv2: same GEMM (K=576) on res_t (f32 -> bf16 staged), BN + channel
// softmax + final out = polar + res*att.
// ---------------------------------------------------------------------------
__global__ __launch_bounds__(256) void k_mconv2(const float* __restrict__ res_t,
                                                const float* __restrict__ polar,
                                                const ushort* __restrict__ wA,
                                                const float* __restrict__ g,
                                                const float* __restrict__ b,
                                                const float* __restrict__ mn,
                                                const float* __restrict__ vr,
                                                float* __restrict__ out) {
    __shared__ __align__(16) ushort xt[3][194][32];
    int tid = threadIdx.x;
    int h = blockIdx.x >> 1, w0 = (blockIdx.x & 1) * 180;
    int wid = tid >> 6, ln = tid & 63;
    f32x4 acc[4][3];
    #pragma unroll
    for (int m = 0; m < 4; m++)
        #pragma unroll
        for (int nf = 0; nf < 3; nf++) acc[m][nf] = (f32x4){0.f, 0.f, 0.f, 0.f};

    for (int c = 0; c < 2; c++) {
        __syncthreads();
        for (int i = tid; i < 2184; i += 256) {
            int q = i & 3, s = i >> 2;
            int r = s / 182, pw = s - r * 182;
            int gh = h + r - 1;
            int gw = w0 + pw - 1;
            if (gw < 0) gw += WW;
            if (gw >= WW) gw -= WW;
            int4_ val = {0, 0, 0, 0};
            if ((unsigned)gh < (unsigned)HH) {
                const float* src = res_t + ((size_t)(gh * WW + gw) * 64 + c * 32 + q * 8);
                f32x4 va = *(const f32x4*)src;
                f32x4 vb = *(const f32x4*)(src + 4);
                uint u0, u1, u2, u3;
                asm("v_cvt_pk_bf16_f32 %0, %1, %2" : "=v"(u0) : "v"(va[0]), "v"(va[1]));
                asm("v_cvt_pk_bf16_f32 %0, %1, %2" : "=v"(u1) : "v"(va[2]), "v"(va[3]));
                asm("v_cvt_pk_bf16_f32 %0, %1, %2" : "=v"(u2) : "v"(vb[0]), "v"(vb[1]));
                asm("v_cvt_pk_bf16_f32 %0, %1, %2" : "=v"(u3) : "v"(vb[2]), "v"(vb[3]));
                val = (int4_){(int)u0, (int)u1, (int)u2, (int)u3};
            }
            *(int4_*)&xt[r][pw][(q ^ (pw & 3)) * 8] = val;
        }
        __syncthreads();
        #pragma unroll
        for (int tap = 0; tap < 9; tap++) {
            int dh = tap / 3, dw = tap % 3;
            short8 aF[4];
            #pragma unroll
            for (int m = 0; m < 4; m++)
                aF[m] = *(const short8*)(wA + (size_t)(((c * 9 + tap) * 4 + m) * 64 + ln) * 8);
            short8 bF[3];
            #pragma unroll
            for (int nf = 0; nf < 3; nf++) {
                int pw = wid * 48 + nf * 16 + (ln & 15) + dw;
                bF[nf] = *(const short8*)&xt[dh][pw][((((ln >> 4) & 3)) ^ (pw & 3)) * 8];
            }
            #pragma unroll
            for (int m = 0; m < 4; m++)
                #pragma unroll
                for (int nf = 0; nf < 3; nf++)
                    acc[m][nf] = __builtin_amdgcn_mfma_f32_16x16x32_bf16(aF[m], bF[nf], acc[m][nf], 0, 0, 0);
        }
    }
    // epilogue: BN -> softmax over 64 channels -> out = polar + res*att
    #pragma unroll
    for (int m = 0; m < 4; m++) {
        #pragma unroll
        for (int reg = 0; reg < 4; reg++) {
            int o = m * 16 + ((ln >> 4) & 3) * 4 + reg;
            float sc = g[o] * rsqrtf(vr[o] + 1e-5f);
            float bi = b[o] - mn[o] * sc;
            #pragma unroll
            for (int nf = 0; nf < 3; nf++)
                acc[m][nf][reg] = fmaf(acc[m][nf][reg], sc, bi);
        }
    }
    #pragma unroll
    for (int nf = 0; nf < 3; nf++) {
        float mx = -3.0e38f;
        #pragma unroll
        for (int m = 0; m < 4; m++)
            #pragma unroll
            for (int reg = 0; reg < 4; reg++) mx = fmaxf(mx, acc[m][nf][reg]);
        mx = fmaxf(mx, __shfl_xor(mx, 16));
        mx = fmaxf(mx, __shfl_xor(mx, 32));
        float s = 0.f;
        #pragma unroll
        for (int m = 0; m < 4; m++)
            #pragma unroll
            for (int reg = 0; reg < 4; reg++) {
                float e = __expf(acc[m][nf][reg] - mx);
                acc[m][nf][reg] = e;
                s += e;
            }
        s += __shfl_xor(s, 16);
        s += __shfl_xor(s, 32);
        float rinv = 1.f / s;
        int n = wid * 48 + nf * 16 + (ln & 15);
        if (n < 180) {
            int P = h * WW + w0 + n;
            #pragma unroll
            for (int m = 0; m < 4; m++)
                #pragma unroll
                for (int reg = 0; reg < 4; reg++) {
                    int o = m * 16 + ((ln >> 4) & 3) * 4 + reg;
                    float att = acc[m][nf][reg] * rinv;
                    out[(size_t)o * NPIX + P] =
                        fmaf(res_t[(size_t)P * 64 + o], att, polar[(size_t)o * NPIX + P]);
                }
        }
    }
}

// ---------------------------------------------------------------------------
extern "C" void kernel_launch(void* const* d_in, const int* in_sizes, int n_in,
                              void* d_out, int out_size, void* d_ws, size_t ws_size,
                              hipStream_t stream) {
    const float* flow  = (const float*)d_in[0];
    const float* polar = (const float*)d_in[1];
    const float* rf    = (const float*)d_in[2];
    const float* fw    = (const float*)d_in[3];
    const float* fg    = (const float*)d_in[4];
    const float* fb    = (const float*)d_in[5];
    const float* fm    = (const float*)d_in[6];
    const float* fv    = (const float*)d_in[7];
    const float* aw    = (const float*)d_in[8];
    const float* ag    = (const float*)d_in[9];
    const float* ab    = (const float*)d_in[10];
    const float* am    = (const float*)d_in[11];
    const float* av    = (const float*)d_in[12];
    float* out = (float*)d_out;

    char* wsb = (char*)d_ws;
    ushort* xin   = (ushort*)wsb;                         // [NPIX][128] bf16 = 44,236,800 B
    ushort* rft   = (ushort*)(wsb + 44236800);            // [RFNPIX][64] bf16 + 256B sentinel lines
    float*  res_t = (float*)(wsb + 61014272);             // [NPIX][64] f32 = 44,236,800 B
    ushort* wA1   = (ushort*)(wsb + 105251072);           // 147,456 B
    ushort* wA2   = wA1 + 73728;                          // 73,728 B

    k_wprep<<<432, 256, 0, stream>>>(fw, aw, wA1, wA2);
    k_tr<<<NPIX / 64, 256, 0, stream>>>(polar, xin, NPIX, 128);
    k_tr<<<RFNPIX / 64, 256, 0, stream>>>(rf, rft, RFNPIX, 64);
    k_zero<<<1, 64, 0, stream>>>((uint*)rft);
    k_sample<<<NPIX / 8, 256, 0, stream>>>(flow, (const char*)rft, xin);
    k_mconv1<<<960, 256, 0, stream>>>(xin, wA1, fg, fb, fm, fv, res_t);
    k_mconv2<<<960, 256, 0, stream>>>(res_t, polar, wA2, ag, ab, am, av, out);
}